// Round 1
// baseline (330.457 us; speedup 1.0000x reference)
//
#include <hip/hip_runtime.h>

#define H 1024
#define E 64
#define BT 64           // tokens per block
#define BK 64           // k-chunk
#define NCH (H / BK)    // 16 chunks
#define EPW 8           // experts per wave (8 waves x 8 experts = 64)

// Scalar-W scheme: lane = token, wave w owns experts w*8..w*8+7.
// x tile staged in LDS (double-buffered, padded stride 68 floats so the
// per-lane row read xs[lane][kk..kk+3] spreads granule-banks: (17*lane+kkf)
// mod 8 covers all 8 groups -> conflict-free b128).
// W comes through the SCALAR pipe: row pointers are wave-uniform
// (readfirstlane on the wave id), so W reads compile to s_load and the
// inner loop is v_fmac_f32 v, v, s -- zero LDS traffic for W.
// Per CU per chunk: LDS ~3.5K cyc < VALU 4.1K cyc -> VALU-bound (~27us floor).
__global__ __launch_bounds__(512, 4) void moe_gate_kernel(
    const float* __restrict__ x, const float* __restrict__ W,
    float* __restrict__ out, int T) {
  __shared__ float xs[2][BT][BK + 4];
  // epilogue logits tile overlays xs (dead after K-loop); 64*65*4 = 16640 B
  float(*ls)[E + 1] = (float(*)[E + 1])xs;

  const int tid = threadIdx.x;
  const int lane = tid & 63;                                   // token
  const int wid = __builtin_amdgcn_readfirstlane(tid >> 6);    // wave 0..7
  const int e0 = wid * EPW;
  const int t0 = blockIdx.x * BT;

  // staging map: 2 float4 per thread (64 rows x 16 granules = 1024 f4)
  const int r0 = tid >> 4;        // 0..31
  const int c0 = tid & 15;
  const int r1 = r0 + 32;         // 32..63
  const float* xp0 = x + (size_t)(t0 + r0) * H + (c0 << 2);
  const float* xp1 = x + (size_t)(t0 + r1) * H + (c0 << 2);

  float acc[EPW];
#pragma unroll
  for (int e = 0; e < EPW; ++e) acc[e] = 0.f;

  // prologue: stage chunk 0
  {
    float4 a = *(const float4*)xp0;
    float4 b = *(const float4*)xp1;
    *(float4*)&xs[0][r0][c0 << 2] = a;
    *(float4*)&xs[0][r1][c0 << 2] = b;
  }
  __syncthreads();

  for (int c = 0; c < NCH; ++c) {
    const int cur = c & 1;
    const bool more = (c + 1 < NCH);
    // issue next chunk's global loads early (T14: latency hides under FMAs)
    float4 na{}, nb{};
    if (more) {
      na = *(const float4*)(xp0 + (c + 1) * BK);
      nb = *(const float4*)(xp1 + (c + 1) * BK);
    }

    // this lane's x row for the chunk: 16 ds_read_b128, conflict-free
    float4 xv[BK / 4];
#pragma unroll
    for (int j = 0; j < BK / 4; ++j)
      xv[j] = *(const float4*)&xs[cur][lane][j << 2];

    // 8 expert rows via scalar loads; 8 independent fmac chains interleave
    const float* Wc = W + (size_t)e0 * H + c * BK;
#pragma unroll
    for (int j = 0; j < BK / 4; ++j) {
#pragma unroll
      for (int e = 0; e < EPW; ++e) {
        float4 wv = *(const float4*)(Wc + (size_t)e * H + (j << 2));  // s_load_dwordx4
        acc[e] = fmaf(xv[j].x, wv.x, acc[e]);
        acc[e] = fmaf(xv[j].y, wv.y, acc[e]);
        acc[e] = fmaf(xv[j].z, wv.z, acc[e]);
        acc[e] = fmaf(xv[j].w, wv.w, acc[e]);
      }
    }

    // write next chunk into the other buffer; one barrier per chunk
    // (buf cur^1 held chunk c-1, all waves finished it before last barrier)
    if (more) {
      *(float4*)&xs[cur ^ 1][r0][c0 << 2] = na;
      *(float4*)&xs[cur ^ 1][r1][c0 << 2] = nb;
    }
    __syncthreads();
  }

  // dump logits tile to LDS for the per-token epilogue (stride 65: conflict-free)
#pragma unroll
  for (int e = 0; e < EPW; ++e) ls[lane][e0 + e] = acc[e];
  __syncthreads();

  // wave 0: one lane per token. top-2 of logits == top-2 of softmax
  // (monotonic); tie-break = lower index first (matches jax.lax.top_k).
  if (tid < BT) {
    const int tk = tid;
    float m1 = -1e30f, m2 = -1e30f;
    int i1 = 0, i2 = 0;
#pragma unroll
    for (int e = 0; e < E; ++e) {
      float v = ls[tk][e];
      if (v > m1) {
        m2 = m1; i2 = i1;
        m1 = v;  i1 = e;
      } else if (v > m2) {
        m2 = v; i2 = e;
      }
    }
    float s = 0.f;
#pragma unroll
    for (int e = 0; e < E; ++e) s += expf(ls[tk][e] - m1);
    float p1 = 1.f / s;                 // exp(m1-m1)/s
    float p2 = expf(m2 - m1) / s;
    // second softmax over [p1, p2] (p1 >= p2 so exponent <= 0: stable)
    float e12 = expf(p2 - p1);
    float s1 = 1.f / (1.f + e12);
    float s2 = e12 * s1;

    size_t t = (size_t)(t0 + tk);
    out[t * 2 + 0] = s1;
    out[t * 2 + 1] = s2;
    float* idxo = out + (size_t)2 * T;
    idxo[t * 2 + 0] = (float)i1;
    idxo[t * 2 + 1] = (float)i2;
  }

  // trailing scalar output: zeros(())
  if (blockIdx.x == 0 && tid == 0) out[(size_t)4 * T] = 0.f;
}

extern "C" void kernel_launch(void* const* d_in, const int* in_sizes, int n_in,
                              void* d_out, int out_size, void* d_ws, size_t ws_size,
                              hipStream_t stream) {
  const float* x = (const float*)d_in[0];
  const float* W = (const float*)d_in[1];
  float* out = (float*)d_out;
  const int T = in_sizes[0] / H;  // 4*8192 = 32768 tokens
  dim3 grid(T / BT), block(512);
  hipLaunchKernelGGL(moe_gate_kernel, grid, block, 0, stream, x, W, out, T);
}